// Round 9
// baseline (346.526 us; speedup 1.0000x reference)
//
#include <hip/hip_runtime.h>

#define BB 32
#define CC 64
#define HH 56
#define WW 56
#define HW 3136
#define TW 64
#define TR 12
#define CS 12   // channel-padded stride (12 dwords): 16B-aligned b128, full 32-bank coverage

// ---------------- pool: 8x8 mean over x[32:64] -> pool[b][32][49] ----------------
__global__ __launch_bounds__(256) void pool_k(const float* __restrict__ x,
                                              float* __restrict__ pool) {
    const int idx = blockIdx.x * 256 + threadIdx.x;
    if (idx >= BB * 32 * 49) return;
    const int l = idx % 49;
    const int bi = idx / 49;
    const int i = bi % 32, b = bi / 32;
    const int py = l / 7, px = l % 7;
    const float4* xp4 = reinterpret_cast<const float4*>(
        x + ((long)(b * CC + 32 + i)) * HW + py * 8 * WW + px * 8);
    float4 sA = make_float4(0.f, 0.f, 0.f, 0.f);
    float4 sB = make_float4(0.f, 0.f, 0.f, 0.f);
    #pragma unroll
    for (int y = 0; y < 8; ++y) {
        const float4 a = xp4[y * 14];
        const float4 c = xp4[y * 14 + 1];
        sA.x += a.x; sA.y += a.y; sA.z += a.z; sA.w += a.w;
        sB.x += c.x; sB.y += c.y; sB.z += c.z; sB.w += c.w;
    }
    pool[idx] = (sA.x + sA.y + sA.z + sA.w + sB.x + sB.y + sB.z + sB.w) * (1.f / 64.f);
}

// ---------------- wkwp: wk matmul+bn -> WK = wp * kg^T, per (b,g) ----------------
__global__ __launch_bounds__(256) void wkwp_k(const float* __restrict__ pool,
                                              const float* __restrict__ wk,
                                              const float* __restrict__ wks,
                                              const float* __restrict__ wkb,
                                              const float* __restrict__ wp_w,
                                              float* __restrict__ WK) {
    __shared__ float p_s[32 * 49];
    __shared__ float kg_s[8 * 49];
    const int b = blockIdx.x >> 2;
    const int g = blockIdx.x & 3;
    const int tid = threadIdx.x;
    for (int idx = tid; idx < 1568; idx += 256) p_s[idx] = pool[b * 1568 + idx];
    __syncthreads();
    for (int idx = tid; idx < 392; idx += 256) {
        const int o8 = idx / 49, l = idx % 49;
        const int o = g * 8 + o8;
        float acc = 0.f;
        #pragma unroll
        for (int i = 0; i < 32; ++i) acc = fmaf(wk[o * 32 + i], p_s[i * 49 + l], acc);
        kg_s[idx] = acc * wks[o] + wkb[o];
    }
    __syncthreads();
    for (int idx = tid; idx < 640; idx += 256) {
        const int c = idx / 80, slot = idx % 80;
        float acc = 0.f;
        int m = -1;
        if (slot < 28) { if (slot < 25) m = slot; }
        else           { if (slot < 77) m = 25 + (slot - 28); }
        if (m >= 0) {
            const float* kp = kg_s + c * 49;
            #pragma unroll
            for (int l = 0; l < 49; ++l) acc = fmaf(wp_w[m * 49 + l], kp[l], acc);
        }
        const long base = (long)blockIdx.x * 640;
        if (slot < 28) WK[base + c * 28 + slot] = acc;
        else           WK[base + 224 + c * 52 + (slot - 28)] = acc;
    }
}

// ---------------- fused q-proj + attention + dyn_mix + lepe ----------------
// Tile layout [row][col][ch] (ch-stride 12): per tap 2x ds_read_b128 gives all 8 channels,
// conflict-free. Block-uniform weights (WK, wq, wp_b, lepe) read via scalar loads from global.
__global__ __launch_bounds__(256) void attnmix_k(const float* __restrict__ x,
                                                 const float* __restrict__ WK,
                                                 const float* __restrict__ wq_w,
                                                 const float* __restrict__ wq_s,
                                                 const float* __restrict__ wq_bb,
                                                 const float* __restrict__ wp_b,
                                                 const float* __restrict__ rpb1,
                                                 const float* __restrict__ rpb2,
                                                 const float* __restrict__ lw,
                                                 const float* __restrict__ lb,
                                                 const float* __restrict__ ls,
                                                 const float* __restrict__ lbb,
                                                 float* __restrict__ mix,
                                                 float* __restrict__ out) {
    __shared__ float tile[TR * TW * CS];   // 36 KB
    __shared__ float rpb1_s[81];
    __shared__ float rpb2_s[169];
    const int tid = threadIdx.x;
    const int bg = blockIdx.y;
    const int g = bg & 3, b = bg >> 2;
    if (tid < 81) rpb1_s[tid] = rpb1[g * 81 + tid];
    if (tid < 169) rpb2_s[tid] = rpb2[g * 169 + tid];

    // block-uniform tables -> scalar loads
    const float* WK1 = WK + (long)bg * 640;
    const float* WK2 = WK1 + 224;
    const float* wqp = wq_w + g * 8 * 32;      // [c][i]
    const float* lw0 = lw + (g * 8) * 49;      // v0 lepe weights [ch][49]
    const float* lw1 = lw + (32 + g * 8) * 49; // v1 lepe weights

    const int N0 = blockIdx.x << 8;
    const int ph0 = N0 / WW;                   // block-uniform
    const int r0 = ph0 - 3;

    // ---- stage v0 tile: tile[k2*CS + ch], k2 = row*64+col ----
    {
        const float* xc = x + ((long)b * CC + g * 8) * HW;
        #pragma unroll
        for (int ch = 0; ch < 8; ++ch) {
            #pragma unroll
            for (int it = 0; it < 3; ++it) {
                const int k2 = tid + it * 256;
                const int row = k2 >> 6, col = k2 & 63;
                const int gy = r0 + row, gx = col - 3;
                float v = 0.f;
                if ((unsigned)gy < HH && (unsigned)gx < WW) v = xc[ch * HW + gy * WW + gx];
                tile[k2 * CS + ch] = v;
            }
        }
    }
    __syncthreads();

    const int n = N0 + tid;
    const bool valid = n < HW;
    const int nc = valid ? n : HW - 1;
    const int ph = nc / WW, pw = nc % WW;
    const int yr = HH - 1 - ph, xr = WW - 1 - pw;
    const int lrow = ph - r0;                  // in [3, 8]

    const float* xb = x + (long)b * CC * HW + nc;

    // ---- q8: q = wq . x[0..32), bn, *SCALE ----
    float q8[8];
    #pragma unroll
    for (int c = 0; c < 8; ++c) q8[c] = 0.f;
    for (int i = 0; i < 32; ++i) {
        const float xv = xb[i * HW];
        #pragma unroll
        for (int c = 0; c < 8; ++c) q8[c] = fmaf(wqp[c * 32 + i], xv, q8[c]);
    }
    #pragma unroll
    for (int c = 0; c < 8; ++c)
        q8[c] = (q8[c] * wq_s[g * 8 + c] + wq_bb[g * 8 + c]) * 0.25f;

    __builtin_amdgcn_sched_barrier(0);

    // ======== phase 1: 25-weight softmax + 5x5 gather + lepe 7x7 over v0 ========
    {
        float w1[25];
        #pragma unroll
        for (int m = 0; m < 25; ++m) w1[m] = wp_b[m];
        #pragma unroll
        for (int c = 0; c < 8; ++c) {
            const float qv = q8[c];
            #pragma unroll
            for (int m = 0; m < 25; ++m) w1[m] = fmaf(qv, WK1[c * 28 + m], w1[m]);
        }
        const int rh5 = yr < 2 ? yr : (yr > 53 ? yr - 51 : 2);
        const int rw5 = xr < 2 ? xr : (xr > 53 ? xr - 51 : 2);
        #pragma unroll
        for (int i = 0; i < 5; ++i)
            #pragma unroll
            for (int j = 0; j < 5; ++j)
                w1[i * 5 + j] += rpb1_s[(rh5 + i) * 9 + (rw5 + j)];
        float mx = -1e30f;
        #pragma unroll
        for (int m = 0; m < 25; ++m) mx = fmaxf(mx, w1[m]);
        float sm = 0.f;
        #pragma unroll
        for (int m = 0; m < 25; ++m) { w1[m] = __expf(w1[m] - mx); sm += w1[m]; }
        const float r = 1.f / sm;
        #pragma unroll
        for (int m = 0; m < 25; ++m) w1[m] *= r;

        float acc[8], lacc[8];
        #pragma unroll
        for (int ch = 0; ch < 8; ++ch) { acc[ch] = 0.f; lacc[ch] = 0.f; }
        #pragma unroll
        for (int i = 0; i < 7; ++i) {
            #pragma unroll
            for (int j = 0; j < 7; ++j) {
                const float* t = &tile[((lrow - 3 + i) * TW + pw + j) * CS];
                const float4 va = *reinterpret_cast<const float4*>(t);
                const float4 vb = *reinterpret_cast<const float4*>(t + 4);
                const float v[8] = {va.x, va.y, va.z, va.w, vb.x, vb.y, vb.z, vb.w};
                #pragma unroll
                for (int ch = 0; ch < 8; ++ch)
                    lacc[ch] = fmaf(lw0[ch * 49 + i * 7 + j], v[ch], lacc[ch]);
                if (i >= 1 && i <= 5 && j >= 1 && j <= 5) {
                    const float wv = w1[(i - 1) * 5 + (j - 1)];
                    #pragma unroll
                    for (int ch = 0; ch < 8; ++ch)
                        acc[ch] = fmaf(wv, v[ch], acc[ch]);
                }
            }
        }
        float* m0 = mix + ((long)b * CC + g * 8) * HW + nc;
        float* o0 = out + ((long)b * CC + g * 8) * HW + nc;
        if (valid) {
            #pragma unroll
            for (int ch = 0; ch < 8; ++ch) {
                m0[ch * HW] = acc[ch];
                o0[ch * HW] = (lacc[ch] + lb[g * 8 + ch]) * ls[g * 8 + ch] + lbb[g * 8 + ch];
            }
        }
    }

    __syncthreads();                      // tile reads done
    // ---- re-stage tile with v1 channels ----
    {
        const float* xc = x + ((long)b * CC + 32 + g * 8) * HW;
        #pragma unroll
        for (int ch = 0; ch < 8; ++ch) {
            #pragma unroll
            for (int it = 0; it < 3; ++it) {
                const int k2 = tid + it * 256;
                const int row = k2 >> 6, col = k2 & 63;
                const int gy = r0 + row, gx = col - 3;
                float v = 0.f;
                if ((unsigned)gy < HH && (unsigned)gx < WW) v = xc[ch * HW + gy * WW + gx];
                tile[k2 * CS + ch] = v;
            }
        }
    }
    __syncthreads();

    // ======== phase 2: 49-weight softmax + 7x7 gather + lepe 7x7 over v1 ========
    {
        float w2[49];
        #pragma unroll
        for (int m = 0; m < 49; ++m) w2[m] = wp_b[25 + m];
        #pragma unroll
        for (int c = 0; c < 8; ++c) {
            const float qv = q8[c];
            #pragma unroll
            for (int m = 0; m < 49; ++m) w2[m] = fmaf(qv, WK2[c * 52 + m], w2[m]);
        }
        const int rh7 = yr < 3 ? yr : (yr > 52 ? yr - 49 : 3);
        const int rw7 = xr < 3 ? xr : (xr > 52 ? xr - 49 : 3);
        #pragma unroll
        for (int i = 0; i < 7; ++i)
            #pragma unroll
            for (int j = 0; j < 7; ++j)
                w2[i * 7 + j] += rpb2_s[(rh7 + i) * 13 + (rw7 + j)];
        float mx = -1e30f;
        #pragma unroll
        for (int m = 0; m < 49; ++m) mx = fmaxf(mx, w2[m]);
        float sm = 0.f;
        #pragma unroll
        for (int m = 0; m < 49; ++m) { w2[m] = __expf(w2[m] - mx); sm += w2[m]; }
        const float r = 1.f / sm;
        #pragma unroll
        for (int m = 0; m < 49; ++m) w2[m] *= r;

        float acc[8], lacc[8];
        #pragma unroll
        for (int ch = 0; ch < 8; ++ch) { acc[ch] = 0.f; lacc[ch] = 0.f; }
        #pragma unroll
        for (int i = 0; i < 7; ++i) {
            #pragma unroll
            for (int j = 0; j < 7; ++j) {
                const float* t = &tile[((lrow - 3 + i) * TW + pw + j) * CS];
                const float4 va = *reinterpret_cast<const float4*>(t);
                const float4 vb = *reinterpret_cast<const float4*>(t + 4);
                const float v[8] = {va.x, va.y, va.z, va.w, vb.x, vb.y, vb.z, vb.w};
                const float wv = w2[i * 7 + j];
                #pragma unroll
                for (int ch = 0; ch < 8; ++ch) {
                    lacc[ch] = fmaf(lw1[ch * 49 + i * 7 + j], v[ch], lacc[ch]);
                    acc[ch] = fmaf(wv, v[ch], acc[ch]);
                }
            }
        }
        float* m1 = mix + ((long)b * CC + 32 + g * 8) * HW + nc;
        float* o1 = out + ((long)b * CC + 32 + g * 8) * HW + nc;
        if (valid) {
            #pragma unroll
            for (int ch = 0; ch < 8; ++ch) {
                m1[ch * HW] = acc[ch];
                o1[ch * HW] = (lacc[ch] + lb[32 + g * 8 + ch]) * ls[32 + g * 8 + ch]
                              + lbb[32 + g * 8 + ch];
            }
        }
    }
}

// ---------------- final: 64x64 channel matmul + bn + lepe add ----------------
__global__ __launch_bounds__(256) void final_k(const float* __restrict__ mix,
                                               const float* __restrict__ dy_w,
                                               const float* __restrict__ s,
                                               const float* __restrict__ bb,
                                               float* __restrict__ out) {
    __shared__ float w_s[64 * 64];      // transposed: w_s[i*64+o] = dy_w[o*64+i]
    const int tid = threadIdx.x;
    const int b = blockIdx.y;
    for (int i = tid; i < 4096; i += 256) w_s[(i & 63) * 64 + (i >> 6)] = dy_w[i];
    __syncthreads();
    const int oo = (tid >> 5) * 8;                  // output octant base
    const int p4 = blockIdx.x * 32 + (tid & 31);    // float4 pixel group, need < 784
    if (p4 >= 784) return;
    const float* mp = mix + (long)b * CC * HW + p4 * 4;
    float4 acc[8];
    #pragma unroll
    for (int o = 0; o < 8; ++o) acc[o] = make_float4(0.f, 0.f, 0.f, 0.f);
    for (int i = 0; i < 64; ++i) {
        const float4 mv = *reinterpret_cast<const float4*>(mp + (long)i * HW);
        const float* wr = w_s + i * 64 + oo;
        #pragma unroll
        for (int o = 0; o < 8; ++o) {
            const float wv = wr[o];
            acc[o].x = fmaf(wv, mv.x, acc[o].x);
            acc[o].y = fmaf(wv, mv.y, acc[o].y);
            acc[o].z = fmaf(wv, mv.z, acc[o].z);
            acc[o].w = fmaf(wv, mv.w, acc[o].w);
        }
    }
    float* op = out + (long)b * CC * HW + p4 * 4;
    #pragma unroll
    for (int o = 0; o < 8; ++o) {
        const float sc = s[oo + o], bc = bb[oo + o];
        float4* dst = reinterpret_cast<float4*>(op + (long)(oo + o) * HW);
        float4 prev = *dst;
        prev.x = fmaf(acc[o].x, sc, bc) + prev.x;
        prev.y = fmaf(acc[o].y, sc, bc) + prev.y;
        prev.z = fmaf(acc[o].z, sc, bc) + prev.z;
        prev.w = fmaf(acc[o].w, sc, bc) + prev.w;
        *dst = prev;
    }
}

extern "C" void kernel_launch(void* const* d_in, const int* in_sizes, int n_in,
                              void* d_out, int out_size, void* d_ws, size_t ws_size,
                              hipStream_t stream) {
    const float* x       = (const float*)d_in[0];
    const float* lepe_w  = (const float*)d_in[1];
    const float* lepe_b  = (const float*)d_in[2];
    const float* lepe_s  = (const float*)d_in[3];
    const float* lepe_bb = (const float*)d_in[4];
    const float* wq_w    = (const float*)d_in[5];
    const float* wq_s    = (const float*)d_in[6];
    const float* wq_bb   = (const float*)d_in[7];
    const float* wk_w    = (const float*)d_in[8];
    const float* wk_s    = (const float*)d_in[9];
    const float* wk_bb   = (const float*)d_in[10];
    const float* wp_w    = (const float*)d_in[11];
    const float* wp_b    = (const float*)d_in[12];
    const float* rpb1    = (const float*)d_in[13];
    const float* rpb2    = (const float*)d_in[14];
    const float* dy_w    = (const float*)d_in[15];
    const float* dy_s    = (const float*)d_in[16];
    const float* dy_bb   = (const float*)d_in[17];
    float* out = (float*)d_out;

    float* ws      = (float*)d_ws;
    float* pool_ws = ws;                              // 32*32*49 = 50176
    float* WK_ws   = pool_ws + 32 * 32 * 49;          // 128*640  = 81920
    float* mix_ws  = WK_ws + 128 * 640;               // 32*64*3136 = 6422528

    const int nTiles = (HW + 255) / 256;              // 13

    pool_k<<<dim3((BB * 32 * 49 + 255) / 256), 256, 0, stream>>>(x, pool_ws);
    wkwp_k<<<dim3(BB * 4), 256, 0, stream>>>(pool_ws, wk_w, wk_s, wk_bb, wp_w, WK_ws);
    attnmix_k<<<dim3(nTiles, BB * 4), 256, 0, stream>>>(x, WK_ws, wq_w, wq_s, wq_bb,
                                                        wp_b, rpb1, rpb2,
                                                        lepe_w, lepe_b, lepe_s, lepe_bb,
                                                        mix_ws, out);
    final_k<<<dim3(25, BB), 256, 0, stream>>>(mix_ws, dy_w, dy_s, dy_bb, out);
}